// Round 2
// baseline (5339.428 us; speedup 1.0000x reference)
//
#include <hip/hip_runtime.h>
#include <cstdint>
#include <cstddef>
#include <initializer_list>

__device__ inline float bf2f(unsigned short h) { return __uint_as_float(((unsigned)h) << 16); }
__device__ inline unsigned short f2bf(float f) {
  unsigned u = __float_as_uint(f);
  u += 0x7fff + ((u >> 16) & 1);
  return (unsigned short)(u >> 16);
}

// ---------------- virtual-A segment for gather-GEMM ----------------
// Each segment is 128 K-rows wide. wk = starting row in W. bf16: base is bf16.
struct Seg { const void* base; const int* idx; const float* scale; int ld; int wk; int bf16; };
struct GemmArgs { Seg segs[7]; const float* addB; const int* addIdx; };

// ---------------- small kernels ----------------
__global__ void k_count(float* dst, const int* __restrict__ idx, int R) {
  int r = blockIdx.x * 256 + threadIdx.x;
  if (r < R) atomicAdd(&dst[idx[r]], 1.0f);
}

__global__ void k_scales(const float* __restrict__ deg, const float* __restrict__ d5,
                         const float* __restrict__ d6, float* deg2, float* dd, int n) {
  int i = blockIdx.x * 256 + threadIdx.x;
  if (i < n) {
    float d = deg[i]; deg2[i] = d * d;
    float a = d5[i], b = d6[i]; dd[i] = a * a + b * b;
  }
}

// out[c*outLd+ch] = sum_{j<k} T[rid*tLd+ch] * (scale?scale[rid]:1), rid = idx?idx[c*k+j]:c*k+j
__global__ void k_gsum(float* __restrict__ out, int outLd,
                       const float* __restrict__ T, int tLd,
                       const float* __restrict__ scale, const int* __restrict__ idx,
                       int k, int nInst) {
  int t = blockIdx.x * 256 + threadIdx.x;
  int c = t >> 7, ch = t & 127;
  if (c >= nInst) return;
  float acc = 0.f;
  int b0 = c * k;
  for (int j = 0; j < k; ++j) {
    int rid = idx ? idx[b0 + j] : b0 + j;
    float v = T[(size_t)rid * tLd + ch];
    if (scale) v *= scale[rid];
    acc += v;
  }
  out[(size_t)c * outLd + ch] = acc;
}

// dst[idx[r]*C + c] += src[(r/div)*C + c]
__global__ void k_scatter(float* __restrict__ dst, const float* __restrict__ src,
                          const int* __restrict__ idx, int R, int C, int div) {
  int r = blockIdx.x;
  if (r >= R) return;
  int n = idx[r];
  const float* s = src + (size_t)(r / div) * C;
  float* d = dst + (size_t)n * C;
  for (int c = threadIdx.x; c < C; c += blockDim.x)
    atomicAdd(&d[c], s[c]);
}

// ---------------- gather-GEMM: C[M,CN] = A_virtual[M, 128*nseg] @ W(+wk rows) ----------------
template <int OUT_BF16>
__launch_bounds__(256)
__global__ void k_gemm(GemmArgs ga, const float* __restrict__ W, int K, int CN,
                       void* __restrict__ Cp, int M) {
  __shared__ float As[32][68];
  __shared__ float Ws[32][64];
  int tid = threadIdx.x;
  int row0 = blockIdx.x * 64, col0 = blockIdx.y * 64;
  int tm = tid >> 4, tn = tid & 15;
  int ar = tid >> 3;               // 0..31
  int ac4 = (tid & 7) << 2;        // 0..28
  int wr = tid >> 4;               // 0..15
  int wc4 = (tid & 15) << 2;       // 0..60
  float acc[4][4] = {};
  for (int k0 = 0; k0 < K; k0 += 32) {
    Seg sg = ga.segs[k0 >> 7];
    int kin = (k0 & 127) + ac4;
#pragma unroll
    for (int h = 0; h < 2; ++h) {
      int arow = ar + h * 32;
      int grow = row0 + arow;
      float4 v = make_float4(0.f, 0.f, 0.f, 0.f);
      if (grow < M) {
        int rid = sg.idx ? sg.idx[grow] : grow;
        if (sg.bf16) {
          const unsigned short* p = (const unsigned short*)sg.base + (size_t)rid * sg.ld + kin;
          ushort4 u = *(const ushort4*)p;
          v.x = bf2f(u.x); v.y = bf2f(u.y); v.z = bf2f(u.z); v.w = bf2f(u.w);
        } else {
          v = *(const float4*)((const float*)sg.base + (size_t)rid * sg.ld + kin);
        }
        if (sg.scale) { float s = sg.scale[rid]; v.x *= s; v.y *= s; v.z *= s; v.w *= s; }
      }
      As[ac4 + 0][arow] = v.x; As[ac4 + 1][arow] = v.y;
      As[ac4 + 2][arow] = v.z; As[ac4 + 3][arow] = v.w;
    }
    int wrow0 = sg.wk + (k0 & 127);
#pragma unroll
    for (int h = 0; h < 2; ++h) {
      int kr = wr + h * 16;
      *(float4*)&Ws[kr][wc4] = *(const float4*)(W + (size_t)(wrow0 + kr) * CN + col0 + wc4);
    }
    __syncthreads();
#pragma unroll
    for (int kk = 0; kk < 32; ++kk) {
      float a[4], b[4];
      *(float4*)a = *(const float4*)&As[kk][tm << 2];
      *(float4*)b = *(const float4*)&Ws[kk][tn << 2];
#pragma unroll
      for (int i = 0; i < 4; ++i)
#pragma unroll
        for (int j = 0; j < 4; ++j)
          acc[i][j] += a[i] * b[j];
    }
    __syncthreads();
  }
#pragma unroll
  for (int i = 0; i < 4; ++i) {
    int grow = row0 + (tm << 2) + i;
    if (grow >= M) continue;
    int col = col0 + (tn << 2);
    float4 o = make_float4(acc[i][0], acc[i][1], acc[i][2], acc[i][3]);
    if (ga.addB) {
      int rid = ga.addIdx ? ga.addIdx[grow] : grow;
      float4 z = *(const float4*)(ga.addB + (size_t)rid * 256 + col);
      o.x += z.x; o.y += z.y; o.z += z.z; o.w += z.w;
    }
    if (OUT_BF16) {
      ushort4 u; u.x = f2bf(o.x); u.y = f2bf(o.y); u.z = f2bf(o.z); u.w = f2bf(o.w);
      *(ushort4*)((unsigned short*)Cp + (size_t)grow * CN + col) = u;
    } else {
      *(float4*)((float*)Cp + (size_t)grow * CN + col) = o;
    }
  }
}

// ---------------- batchnorm (training stats) + ReLU ----------------
template <int SB>
__global__ void k_bnstats(const void* __restrict__ yv, int M, int C,
                          float* __restrict__ stats, int rpb) {
  int c = threadIdx.x;
  int r0 = blockIdx.x * rpb;
  int r1 = min(M, r0 + rpb);
  float s = 0.f, q = 0.f;
  for (int r = r0; r < r1; ++r) {
    float v = SB ? bf2f(((const unsigned short*)yv)[(size_t)r * C + c])
                 : ((const float*)yv)[(size_t)r * C + c];
    s += v; q += v * v;
  }
  atomicAdd(&stats[c], s);
  atomicAdd(&stats[C + c], q);
}

template <int SB, int DB>
__global__ void k_bnapply(void* __restrict__ dst, const void* __restrict__ yv,
                          const float* __restrict__ g, const float* __restrict__ b,
                          const float* __restrict__ stats, int M, int C) {
  int t = blockIdx.x * 256 + threadIdx.x;
  if (t >= M * C) return;
  int c = t & (C - 1);
  float inv = 1.0f / (float)M;
  float m = stats[c] * inv;
  float v = stats[C + c] * inv - m * m;
  float sc = g[c] * rsqrtf(v + 1e-5f);
  float sh = b[c] - m * sc;
  float x = SB ? bf2f(((const unsigned short*)yv)[t]) : ((const float*)yv)[t];
  x = x * sc + sh;
  x = x > 0.f ? x : 0.f;
  if (DB) ((unsigned short*)dst)[t] = f2bf(x);
  else    ((float*)dst)[t] = x;
}

// ---------------- host ----------------
extern "C" void kernel_launch(void* const* d_in, const int* in_sizes, int n_in,
                              void* d_out, int out_size, void* d_ws, size_t ws_size,
                              hipStream_t stream) {
  constexpr int N = 50000, E = 100000, C5 = 8000, C6 = 12000;
  constexpr int RE = 2 * E, R5 = 5 * C5, R6 = 6 * C6, NC = R5 + R6, CC = C5 + C6;

  const float* node_rep  = (const float*)d_in[0];
  const float* edge_rep  = (const float*)d_in[1];
  const float* cycle_rep = (const float*)d_in[2];
  const int* en  = (const int*)d_in[3];
  const int* cn5 = (const int*)d_in[4];
  const int* cn6 = (const int*)d_in[5];
  const float* nm_w1 = (const float*)d_in[6],  *nm_g1 = (const float*)d_in[7],  *nm_b1 = (const float*)d_in[8];
  const float* nm_w2 = (const float*)d_in[9],  *nm_g2 = (const float*)d_in[10], *nm_b2 = (const float*)d_in[11];
  const float* em_w1 = (const float*)d_in[12], *em_g1 = (const float*)d_in[13], *em_b1 = (const float*)d_in[14];
  const float* em_w2 = (const float*)d_in[15], *em_g2 = (const float*)d_in[16], *em_b2 = (const float*)d_in[17];
  const float* ce_w1 = (const float*)d_in[18], *ce_g1 = (const float*)d_in[19], *ce_b1 = (const float*)d_in[20];
  const float* ce_w2 = (const float*)d_in[21], *ce_g2 = (const float*)d_in[22], *ce_b2 = (const float*)d_in[23];
  const float* cm_w1 = (const float*)d_in[24], *cm_g1 = (const float*)d_in[25], *cm_b1 = (const float*)d_in[26];
  const float* cm_w2 = (const float*)d_in[27], *cm_g2 = (const float*)d_in[28], *cm_b2 = (const float*)d_in[29];
  const float* fm_w  = (const float*)d_in[30], *fm_g  = (const float*)d_in[31], *fm_b  = (const float*)d_in[32];
  float* outD = (float*)d_out;
  float* outN = outD;
  float* outE = outD + (size_t)N * 128;
  float* outC = outD + (size_t)(N + RE) * 128;

  // ---- byte-granular arena ----
  char* wsb = (char*)d_ws;
  size_t off = 0;
  auto A = [&](size_t bytes) { void* p = wsb + off; off += (bytes + 255) & ~(size_t)255; return p; };
  float* deg = (float*)A(N * 4);
  float* d5  = (float*)A(N * 4);
  float* d6  = (float*)A(N * 4);
  float* Ae  = (float*)A((size_t)N * 128 * 4);
  float* Be  = (float*)A((size_t)N * 128 * 4);
  float* Bn  = (float*)A((size_t)N * 128 * 4);
  float* pb2 = (float*)A((size_t)N * 256 * 4);
  float* pb5 = (float*)A((size_t)N * 256 * 4);
  float* pb6 = (float*)A((size_t)N * 256 * 4);
  float* Ac  = (float*)A((size_t)N * 128 * 4);
  size_t zeroBytes = off;                       // everything above is scatter-target
  float* deg2 = (float*)A(N * 4);
  float* dd   = (float*)A(N * 4);
  float* Z    = (float*)A((size_t)N * 256 * 4);
  float* stats = (float*)A(512 * 4);
  char*  Yb   = (char*)A((size_t)RE * 256 * 2); // bf16 y arena; aliased as fp32 staging
  unsigned short* O2 = (unsigned short*)A((size_t)RE * 128 * 2);
  if (off > ws_size) return;                    // ~462 MB required

  // staging views inside Yb (liveness-disjoint with bf16 y use)
  float* s2 = (float*)Yb;               // [E,128]
  float* sN = s2 + (size_t)E * 128;     // [E,128]
  float* s3 = (float*)Yb;               // [E,256]
  float* s5 = (float*)Yb;               // [C5,256]
  float* s6 = s5 + (size_t)C5 * 256;    // [C6,256]
  float* scb = (float*)Yb;              // [CC,640]
  float* Ysc = scb + (size_t)CC * 640;  // [CC,256]

  auto gsum = [&](float* o, int oLd, const float* T, int tLd,
                  const float* scl, const int* idx, int k, int nInst) {
    int tot = nInst * 128;
    k_gsum<<<(tot + 255) / 256, 256, 0, stream>>>(o, oLd, T, tLd, scl, idx, k, nInst);
  };
  auto scat = [&](float* dst, const float* src, const int* idx, int R, int C, int dv) {
    k_scatter<<<R, 128, 0, stream>>>(dst, src, idx, R, C, dv);
  };
  auto gemm = [&](std::initializer_list<Seg> segs, const float* W, int CN, void* Co,
                  int M, bool outBf, const float* addB, const int* addIdx) {
    GemmArgs ga{}; int i = 0;
    for (const Seg& s : segs) ga.segs[i++] = s;
    ga.addB = addB; ga.addIdx = addIdx;
    int K = i * 128;
    dim3 g((M + 63) / 64, CN / 64);
    if (outBf) k_gemm<1><<<g, 256, 0, stream>>>(ga, W, K, CN, Co, M);
    else       k_gemm<0><<<g, 256, 0, stream>>>(ga, W, K, CN, Co, M);
  };
  auto bn = [&](const void* y, void* dst, const float* g, const float* b,
                int M, int C, int sb, int db) {
    hipMemsetAsync(stats, 0, 2 * C * sizeof(float), stream);
    int rpb = 256, nb = (M + rpb - 1) / rpb, tot = M * C, gb = (tot + 255) / 256;
    if (sb) k_bnstats<1><<<nb, C, 0, stream>>>(y, M, C, stats, rpb);
    else    k_bnstats<0><<<nb, C, 0, stream>>>(y, M, C, stats, rpb);
    if (sb && db)       k_bnapply<1, 1><<<gb, 256, 0, stream>>>(dst, y, g, b, stats, M, C);
    else if (sb && !db) k_bnapply<1, 0><<<gb, 256, 0, stream>>>(dst, y, g, b, stats, M, C);
    else if (!sb && db) k_bnapply<0, 1><<<gb, 256, 0, stream>>>(dst, y, g, b, stats, M, C);
    else                k_bnapply<0, 0><<<gb, 256, 0, stream>>>(dst, y, g, b, stats, M, C);
  };

  // ---- phase 0: degrees ----
  hipMemsetAsync(d_ws, 0, zeroBytes, stream);
  k_count<<<(RE + 255) / 256, 256, 0, stream>>>(deg, en, RE);
  k_count<<<(R5 + 255) / 256, 256, 0, stream>>>(d5, cn5, R5);
  k_count<<<(R6 + 255) / 256, 256, 0, stream>>>(d6, cn6, R6);
  k_scales<<<(N + 255) / 256, 256, 0, stream>>>(deg, d5, d6, deg2, dd, N);

  // ---- phase 1: edge-node tables ----
  gsum(s2, 128, edge_rep, 128, nullptr, nullptr, 2, E);
  gsum(sN, 128, node_rep, 128, nullptr, en, 2, E);
  scat(Ae, edge_rep, en, RE, 128, 1);
  scat(Be, s2, en, RE, 128, 2);
  scat(Bn, sN, en, RE, 128, 2);
  gsum(s3, 256, Ae, 128, nullptr, en, 2, E);
  gsum(s3 + 128, 256, Be, 128, nullptr, en, 2, E);
  scat(pb2, s3, en, RE, 256, 2);

  // ---- phase 2: cycle tables ----
  gsum(s5, 256, Ae, 128, nullptr, cn5, 5, C5);
  gsum(s5 + 128, 256, Be, 128, nullptr, cn5, 5, C5);
  gsum(s6, 256, Ae, 128, nullptr, cn6, 6, C6);
  gsum(s6 + 128, 256, Be, 128, nullptr, cn6, 6, C6);
  scat(pb5, s5, cn5, R5, 256, 5);
  scat(pb6, s6, cn6, R6, 256, 6);
  scat(Ac, cycle_rep, cn5, R5, 128, 1);
  scat(Ac, cycle_rep + (size_t)R5 * 128, cn6, R6, 128, 1);

  // ---- ce stage ----
  gsum(scb + 0,   640, Ae, 128, d5, cn5, 5, C5);
  gsum(scb + 128, 640, Be, 128, d5, cn5, 5, C5);
  gsum(scb + 256, 640, pb5, 256, nullptr, cn5, 5, C5);
  gsum(scb + 384, 640, pb5 + 128, 256, nullptr, cn5, 5, C5);
  gsum(scb + 512, 640, cycle_rep, 128, nullptr, nullptr, 5, C5);
  float* sc6 = scb + (size_t)C5 * 640;
  gsum(sc6 + 0,   640, Ae, 128, d6, cn6, 6, C6);
  gsum(sc6 + 128, 640, Be, 128, d6, cn6, 6, C6);
  gsum(sc6 + 256, 640, pb6, 256, nullptr, cn6, 6, C6);
  gsum(sc6 + 384, 640, pb6 + 128, 256, nullptr, cn6, 6, C6);
  gsum(sc6 + 512, 640, cycle_rep + (size_t)R5 * 128, 128, nullptr, nullptr, 6, C6);
  gemm({{scb, nullptr, nullptr, 640, 768, 0}, {scb + 128, nullptr, nullptr, 640, 896, 0},
        {scb + 256, nullptr, nullptr, 640, 1024, 0}, {scb + 384, nullptr, nullptr, 640, 1152, 0},
        {scb + 512, nullptr, nullptr, 640, 1280, 0}},
       ce_w1, 256, Ysc, CC, false, nullptr, nullptr);
  gemm({{Ae, nullptr, dd, 128, 128, 0}, {Be, nullptr, dd, 128, 256, 0},
        {pb5, nullptr, d5, 256, 384, 0}, {pb5 + 128, nullptr, d5, 256, 512, 0},
        {pb6, nullptr, d6, 256, 384, 0}, {pb6 + 128, nullptr, d6, 256, 512, 0},
        {Ac, nullptr, nullptr, 128, 640, 0}},
       ce_w1, 256, Z, N, false, nullptr, nullptr);
  scat(Z, Ysc, cn5, R5, 256, 5);
  scat(Z, Ysc + (size_t)C5 * 256, cn6, R6, 256, 6);
  gemm({{edge_rep, nullptr, nullptr, 128, 0, 0}}, ce_w1, 256, Yb, RE, true, Z, en);
  bn(Yb, Yb, ce_g1, ce_b1, RE, 256, 1, 1);
  gemm({{Yb, nullptr, nullptr, 256, 0, 1}, {Yb + 256, nullptr, nullptr, 256, 128, 1}},
       ce_w2, 128, O2, RE, true, nullptr, nullptr);
  bn(O2, O2, ce_g2, ce_b2, RE, 128, 1, 1);

  // ---- em stage ----
  gemm({{Ae, nullptr, deg, 128, 128, 0}, {Be, nullptr, deg, 128, 256, 0},
        {pb2, nullptr, nullptr, 256, 384, 0}, {pb2 + 128, nullptr, nullptr, 256, 512, 0},
        {node_rep, nullptr, deg, 128, 640, 0}, {Bn, nullptr, nullptr, 128, 768, 0}},
       em_w1, 256, Z, N, false, nullptr, nullptr);
  gemm({{edge_rep, nullptr, nullptr, 128, 0, 0}}, em_w1, 256, Yb, RE, true, Z, en);
  bn(Yb, Yb, em_g1, em_b1, RE, 256, 1, 1);
  gemm({{Yb, nullptr, nullptr, 256, 0, 1}, {Yb + 256, nullptr, nullptr, 256, 128, 1}},
       em_w2, 128, outE, RE, false, nullptr, nullptr);   // out1 -> outD edge region (scratch)
  bn(outE, outE, em_g2, em_b2, RE, 128, 0, 0);

  // ---- nm stage ----
  gemm({{node_rep, nullptr, nullptr, 128, 0, 0}, {Ae, nullptr, deg2, 128, 128, 0},
        {Be, nullptr, deg2, 128, 256, 0}, {pb2, nullptr, deg, 256, 384, 0},
        {pb2 + 128, nullptr, deg, 256, 512, 0}, {node_rep, nullptr, deg2, 128, 640, 0},
        {Bn, nullptr, deg, 128, 768, 0}},
       nm_w1, 256, Yb, N, true, nullptr, nullptr);
  bn(Yb, Yb, nm_g1, nm_b1, N, 256, 1, 1);
  gemm({{Yb, nullptr, nullptr, 256, 0, 1}, {Yb + 256, nullptr, nullptr, 256, 128, 1}},
       nm_w2, 128, outN, N, false, nullptr, nullptr);
  bn(outN, outN, nm_g2, nm_b2, N, 128, 0, 0);

  // ---- cm stage ----
  gemm({{Ae, nullptr, d5, 128, 0, 0}, {Be, nullptr, d5, 128, 128, 0},
        {pb5, nullptr, nullptr, 256, 256, 0}, {pb5 + 128, nullptr, nullptr, 256, 384, 0}},
       cm_w1, 256, Z, N, false, nullptr, nullptr);
  gemm({{cycle_rep, nullptr, nullptr, 128, 512, 0}}, cm_w1, 256, Yb, R5, true, Z, cn5);
  gemm({{Ae, nullptr, d6, 128, 0, 0}, {Be, nullptr, d6, 128, 128, 0},
        {pb6, nullptr, nullptr, 256, 256, 0}, {pb6 + 128, nullptr, nullptr, 256, 384, 0}},
       cm_w1, 256, Z, N, false, nullptr, nullptr);
  gemm({{cycle_rep + (size_t)R5 * 128, nullptr, nullptr, 128, 512, 0}}, cm_w1, 256,
       Yb + (size_t)R5 * 256 * 2, R6, true, Z, cn6);
  bn(Yb, Yb, cm_g1, cm_b1, NC, 256, 1, 1);
  gemm({{Yb, nullptr, nullptr, 256, 0, 1}, {Yb + 256, nullptr, nullptr, 256, 128, 1}},
       cm_w2, 128, outC, NC, false, nullptr, nullptr);
  bn(outC, outC, cm_g2, cm_b2, NC, 128, 0, 0);

  // ---- fm stage ----
  gemm({{outE, nullptr, nullptr, 128, 0, 0}, {O2, nullptr, nullptr, 128, 128, 1}},
       fm_w, 128, Yb, RE, true, nullptr, nullptr);
  bn(Yb, outE, fm_g, fm_b, RE, 128, 1, 0);
}

// Round 3
// 3897.165 us; speedup vs baseline: 1.3701x; 1.3701x over previous
//
#include <hip/hip_runtime.h>
#include <cstdint>
#include <cstddef>
#include <initializer_list>

typedef short bf16x8 __attribute__((ext_vector_type(8)));
typedef float f32x4 __attribute__((ext_vector_type(4)));

__device__ inline float bf2f(unsigned short h) { return __uint_as_float(((unsigned)h) << 16); }
__device__ inline unsigned short f2bf(float f) {
  unsigned u = __float_as_uint(f);
  u += 0x7fff + ((u >> 16) & 1);
  return (unsigned short)(u >> 16);
}

// ---------------- virtual-A segment for gather-GEMM ----------------
// Each segment is 128 K-rows wide. wk = starting row in W (= col offset in Wt). bf16: base is bf16.
struct Seg { const void* base; const int* idx; const float* scale; int ld; int wk; int bf16; };
struct GemmArgs { Seg segs[7]; const float* addB; const int* addIdx; };

// ---------------- small kernels ----------------
__global__ void k_count(float* dst, const int* __restrict__ idx, int R) {
  int r = blockIdx.x * 256 + threadIdx.x;
  if (r < R) atomicAdd(&dst[idx[r]], 1.0f);
}

__global__ void k_scales(const float* __restrict__ deg, const float* __restrict__ d5,
                         const float* __restrict__ d6, float* deg2, float* dd, int n) {
  int i = blockIdx.x * 256 + threadIdx.x;
  if (i < n) {
    float d = deg[i]; deg2[i] = d * d;
    float a = d5[i], b = d6[i]; dd[i] = a * a + b * b;
  }
}

__global__ void k_wtrans(const float* __restrict__ W, unsigned short* __restrict__ Wt,
                         int K, int CN) {
  int t = blockIdx.x * 256 + threadIdx.x;
  if (t >= K * CN) return;
  int k = t / CN, n = t - k * CN;
  Wt[(size_t)n * K + k] = f2bf(W[t]);
}

// out[c*outLd+ch] = sum_{j<k} T[rid*tLd+ch] * (scale?scale[rid]:1), rid = idx?idx[c*k+j]:c*k+j
__global__ void k_gsum(float* __restrict__ out, int outLd,
                       const float* __restrict__ T, int tLd,
                       const float* __restrict__ scale, const int* __restrict__ idx,
                       int k, int nInst) {
  int t = blockIdx.x * 256 + threadIdx.x;
  int c = t >> 7, ch = t & 127;
  if (c >= nInst) return;
  float acc = 0.f;
  int b0 = c * k;
  for (int j = 0; j < k; ++j) {
    int rid = idx ? idx[b0 + j] : b0 + j;
    float v = T[(size_t)rid * tLd + ch];
    if (scale) v *= scale[rid];
    acc += v;
  }
  out[(size_t)c * outLd + ch] = acc;
}

// dst[idx[r]*C + c] += src[(r/div)*C + c]
__global__ void k_scatter(float* __restrict__ dst, const float* __restrict__ src,
                          const int* __restrict__ idx, int R, int C, int div) {
  int r = blockIdx.x;
  if (r >= R) return;
  int n = idx[r];
  const float* s = src + (size_t)(r / div) * C;
  float* d = dst + (size_t)n * C;
  for (int c = threadIdx.x; c < C; c += blockDim.x)
    atomicAdd(&d[c], s[c]);
}

// ---------------- MFMA gather-GEMM: C[M,CN] = A_virtual[M, 128*nseg] @ W ----------------
// 128x128 tile, BK=32, 256 thr = 4 waves (2x2), mfma_f32_16x16x32_bf16, 4x4 acc/wave.
// LDS: A[m][k] and B(=Wt)[n][k] bf16, 64B row stride, XOR chunk swizzle (2-way = free).
template <int OUT_BF16>
__launch_bounds__(256)
__global__ void k_gemm(GemmArgs ga, const unsigned short* __restrict__ Wt, int Ktot,
                       int K, int CN, void* __restrict__ Cp, int M) {
  __shared__ char AsB[128 * 64];
  __shared__ char BsB[128 * 64];
  int tid = threadIdx.x;
  int row0 = blockIdx.x * 128, col0 = blockIdx.y * 128;
  int l = tid & 63, w = tid >> 6;
  int wm = w >> 1, wn = w & 1;
  int lr = l & 15, g = l >> 4;
  int chunkOff = (g ^ ((lr >> 1) & 3)) << 4;
  int sm = tid >> 2;          // staging row 0..63 (+64h)
  int sc = tid & 3;           // staging 16B chunk
  f32x4 acc[4][4] = {};
  for (int k0 = 0; k0 < K; k0 += 32) {
    Seg sg = ga.segs[k0 >> 7];
    int kin = k0 & 127;
#pragma unroll
    for (int h = 0; h < 2; ++h) {
      int m = sm + 64 * h;
      int grow = row0 + m;
      uint4 pk = make_uint4(0, 0, 0, 0);
      if (grow < M) {
        int rid = sg.idx ? sg.idx[grow] : grow;
        if (sg.bf16) {
          pk = *(const uint4*)((const unsigned short*)sg.base + (size_t)rid * sg.ld + kin + sc * 8);
        } else {
          const float* fp = (const float*)sg.base + (size_t)rid * sg.ld + kin + sc * 8;
          float4 v0 = *(const float4*)fp;
          float4 v1 = *(const float4*)(fp + 4);
          if (sg.scale) {
            float s = sg.scale[rid];
            v0.x *= s; v0.y *= s; v0.z *= s; v0.w *= s;
            v1.x *= s; v1.y *= s; v1.z *= s; v1.w *= s;
          }
          pk.x = f2bf(v0.x) | ((unsigned)f2bf(v0.y) << 16);
          pk.y = f2bf(v0.z) | ((unsigned)f2bf(v0.w) << 16);
          pk.z = f2bf(v1.x) | ((unsigned)f2bf(v1.y) << 16);
          pk.w = f2bf(v1.z) | ((unsigned)f2bf(v1.w) << 16);
        }
      }
      *(uint4*)(AsB + m * 64 + ((sc ^ ((m >> 1) & 3)) << 4)) = pk;
      // stage B from pre-transposed bf16 Wt[n][Ktot]
      int ng = col0 + m;
      uint4 bp = *(const uint4*)(Wt + (size_t)ng * Ktot + sg.wk + kin + sc * 8);
      *(uint4*)(BsB + m * 64 + ((sc ^ ((m >> 1) & 3)) << 4)) = bp;
    }
    __syncthreads();
    bf16x8 a[4], b[4];
#pragma unroll
    for (int i = 0; i < 4; ++i) {
      int m = wm * 64 + i * 16 + lr;
      a[i] = *(const bf16x8*)(AsB + m * 64 + chunkOff);
    }
#pragma unroll
    for (int j = 0; j < 4; ++j) {
      int n = wn * 64 + j * 16 + lr;
      b[j] = *(const bf16x8*)(BsB + n * 64 + chunkOff);
    }
#pragma unroll
    for (int i = 0; i < 4; ++i)
#pragma unroll
      for (int j = 0; j < 4; ++j)
        acc[i][j] = __builtin_amdgcn_mfma_f32_16x16x32_bf16(a[i], b[j], acc[i][j], 0, 0, 0);
    __syncthreads();
  }
  // epilogue: C/D layout col=lane&15, row=(lane>>4)*4+reg (m89-verified)
#pragma unroll
  for (int i = 0; i < 4; ++i) {
#pragma unroll
    for (int r = 0; r < 4; ++r) {
      int grow = row0 + wm * 64 + i * 16 + g * 4 + r;
      if (grow >= M) continue;
      const float* zr = nullptr;
      if (ga.addB) {
        int rid = ga.addIdx ? ga.addIdx[grow] : grow;
        zr = ga.addB + (size_t)rid * 256;
      }
#pragma unroll
      for (int j = 0; j < 4; ++j) {
        int col = col0 + wn * 64 + j * 16 + lr;
        float o = acc[i][j][r];
        if (zr) o += zr[col];
        if (OUT_BF16) ((unsigned short*)Cp)[(size_t)grow * CN + col] = f2bf(o);
        else          ((float*)Cp)[(size_t)grow * CN + col] = o;
      }
    }
  }
}

// ---------------- batchnorm (training stats) + ReLU ----------------
template <int SB>
__global__ void k_bnstats(const void* __restrict__ yv, int M, int C,
                          float* __restrict__ stats, int rpb) {
  int c = threadIdx.x;
  int r0 = blockIdx.x * rpb;
  int r1 = min(M, r0 + rpb);
  float s = 0.f, q = 0.f;
  for (int r = r0; r < r1; ++r) {
    float v = SB ? bf2f(((const unsigned short*)yv)[(size_t)r * C + c])
                 : ((const float*)yv)[(size_t)r * C + c];
    s += v; q += v * v;
  }
  atomicAdd(&stats[c], s);
  atomicAdd(&stats[C + c], q);
}

template <int SB, int DB>
__global__ void k_bnapply(void* __restrict__ dst, const void* __restrict__ yv,
                          const float* __restrict__ g, const float* __restrict__ b,
                          const float* __restrict__ stats, int M, int C) {
  int t = blockIdx.x * 256 + threadIdx.x;
  if (t >= M * C) return;
  int c = t & (C - 1);
  float inv = 1.0f / (float)M;
  float m = stats[c] * inv;
  float v = stats[C + c] * inv - m * m;
  float sc = g[c] * rsqrtf(v + 1e-5f);
  float sh = b[c] - m * sc;
  float x = SB ? bf2f(((const unsigned short*)yv)[t]) : ((const float*)yv)[t];
  x = x * sc + sh;
  x = x > 0.f ? x : 0.f;
  if (DB) ((unsigned short*)dst)[t] = f2bf(x);
  else    ((float*)dst)[t] = x;
}

// ---------------- host ----------------
extern "C" void kernel_launch(void* const* d_in, const int* in_sizes, int n_in,
                              void* d_out, int out_size, void* d_ws, size_t ws_size,
                              hipStream_t stream) {
  constexpr int N = 50000, E = 100000, C5 = 8000, C6 = 12000;
  constexpr int RE = 2 * E, R5 = 5 * C5, R6 = 6 * C6, NC = R5 + R6, CC = C5 + C6;

  const float* node_rep  = (const float*)d_in[0];
  const float* edge_rep  = (const float*)d_in[1];
  const float* cycle_rep = (const float*)d_in[2];
  const int* en  = (const int*)d_in[3];
  const int* cn5 = (const int*)d_in[4];
  const int* cn6 = (const int*)d_in[5];
  const float* nm_w1 = (const float*)d_in[6],  *nm_g1 = (const float*)d_in[7],  *nm_b1 = (const float*)d_in[8];
  const float* nm_w2 = (const float*)d_in[9],  *nm_g2 = (const float*)d_in[10], *nm_b2 = (const float*)d_in[11];
  const float* em_w1 = (const float*)d_in[12], *em_g1 = (const float*)d_in[13], *em_b1 = (const float*)d_in[14];
  const float* em_w2 = (const float*)d_in[15], *em_g2 = (const float*)d_in[16], *em_b2 = (const float*)d_in[17];
  const float* ce_w1 = (const float*)d_in[18], *ce_g1 = (const float*)d_in[19], *ce_b1 = (const float*)d_in[20];
  const float* ce_w2 = (const float*)d_in[21], *ce_g2 = (const float*)d_in[22], *ce_b2 = (const float*)d_in[23];
  const float* cm_w1 = (const float*)d_in[24], *cm_g1 = (const float*)d_in[25], *cm_b1 = (const float*)d_in[26];
  const float* cm_w2 = (const float*)d_in[27], *cm_g2 = (const float*)d_in[28], *cm_b2 = (const float*)d_in[29];
  const float* fm_w  = (const float*)d_in[30], *fm_g  = (const float*)d_in[31], *fm_b  = (const float*)d_in[32];
  float* outD = (float*)d_out;
  float* outN = outD;
  float* outE = outD + (size_t)N * 128;
  float* outC = outD + (size_t)(N + RE) * 128;

  // ---- byte-granular arena ----
  char* wsb = (char*)d_ws;
  size_t off = 0;
  auto A = [&](size_t bytes) { void* p = wsb + off; off += (bytes + 255) & ~(size_t)255; return p; };
  float* deg = (float*)A(N * 4);
  float* d5  = (float*)A(N * 4);
  float* d6  = (float*)A(N * 4);
  float* Ae  = (float*)A((size_t)N * 128 * 4);
  float* Be  = (float*)A((size_t)N * 128 * 4);
  float* Bn  = (float*)A((size_t)N * 128 * 4);
  float* pb2 = (float*)A((size_t)N * 256 * 4);
  float* pb5 = (float*)A((size_t)N * 256 * 4);
  float* pb6 = (float*)A((size_t)N * 256 * 4);
  float* Ac  = (float*)A((size_t)N * 128 * 4);
  size_t zeroBytes = off;                       // everything above is scatter-target
  float* deg2 = (float*)A(N * 4);
  float* dd   = (float*)A(N * 4);
  float* Z    = (float*)A((size_t)N * 256 * 4);
  float* stats = (float*)A(512 * 4);
  // bf16 transposed weights
  unsigned short* WtNm1 = (unsigned short*)A((size_t)896 * 256 * 2);
  unsigned short* WtEm1 = (unsigned short*)A((size_t)896 * 256 * 2);
  unsigned short* WtCe1 = (unsigned short*)A((size_t)1408 * 256 * 2);
  unsigned short* WtCm1 = (unsigned short*)A((size_t)640 * 256 * 2);
  unsigned short* WtNm2 = (unsigned short*)A((size_t)256 * 128 * 2);
  unsigned short* WtEm2 = (unsigned short*)A((size_t)256 * 128 * 2);
  unsigned short* WtCe2 = (unsigned short*)A((size_t)256 * 128 * 2);
  unsigned short* WtCm2 = (unsigned short*)A((size_t)256 * 128 * 2);
  unsigned short* WtFm  = (unsigned short*)A((size_t)256 * 128 * 2);
  char*  Yb   = (char*)A((size_t)RE * 256 * 2); // bf16 y arena; aliased as fp32 staging
  unsigned short* O2 = (unsigned short*)A((size_t)RE * 128 * 2);
  if (off > ws_size) return;                    // ~465 MB required

  // staging views inside Yb (liveness-disjoint with bf16 y use)
  float* s2 = (float*)Yb;               // [E,128]
  float* sN = s2 + (size_t)E * 128;     // [E,128]
  float* s3 = (float*)Yb;               // [E,256]
  float* s5 = (float*)Yb;               // [C5,256]
  float* s6 = s5 + (size_t)C5 * 256;    // [C6,256]
  float* scb = (float*)Yb;              // [CC,640]
  float* Ysc = scb + (size_t)CC * 640;  // [CC,256]

  auto gsum = [&](float* o, int oLd, const float* T, int tLd,
                  const float* scl, const int* idx, int k, int nInst) {
    int tot = nInst * 128;
    k_gsum<<<(tot + 255) / 256, 256, 0, stream>>>(o, oLd, T, tLd, scl, idx, k, nInst);
  };
  auto scat = [&](float* dst, const float* src, const int* idx, int R, int C, int dv) {
    k_scatter<<<R, 128, 0, stream>>>(dst, src, idx, R, C, dv);
  };
  auto wtr = [&](const float* W, unsigned short* Wt, int K, int CN) {
    k_wtrans<<<(K * CN + 255) / 256, 256, 0, stream>>>(W, Wt, K, CN);
  };
  auto gemm = [&](std::initializer_list<Seg> segs, const unsigned short* Wt, int Ktot,
                  int CN, void* Co, int M, bool outBf, const float* addB, const int* addIdx) {
    GemmArgs ga{}; int i = 0;
    for (const Seg& s : segs) ga.segs[i++] = s;
    ga.addB = addB; ga.addIdx = addIdx;
    int K = i * 128;
    dim3 g((M + 127) / 128, CN / 128);
    if (outBf) k_gemm<1><<<g, 256, 0, stream>>>(ga, Wt, Ktot, K, CN, Co, M);
    else       k_gemm<0><<<g, 256, 0, stream>>>(ga, Wt, Ktot, K, CN, Co, M);
  };
  auto bn = [&](const void* y, void* dst, const float* g, const float* b,
                int M, int C, int sb, int db) {
    hipMemsetAsync(stats, 0, 2 * C * sizeof(float), stream);
    int rpb = 256, nb = (M + rpb - 1) / rpb, tot = M * C, gb = (tot + 255) / 256;
    if (sb) k_bnstats<1><<<nb, C, 0, stream>>>(y, M, C, stats, rpb);
    else    k_bnstats<0><<<nb, C, 0, stream>>>(y, M, C, stats, rpb);
    if (sb && db)       k_bnapply<1, 1><<<gb, 256, 0, stream>>>(dst, y, g, b, stats, M, C);
    else if (sb && !db) k_bnapply<1, 0><<<gb, 256, 0, stream>>>(dst, y, g, b, stats, M, C);
    else if (!sb && db) k_bnapply<0, 1><<<gb, 256, 0, stream>>>(dst, y, g, b, stats, M, C);
    else                k_bnapply<0, 0><<<gb, 256, 0, stream>>>(dst, y, g, b, stats, M, C);
  };

  // ---- phase 0: degrees + weight transposes ----
  hipMemsetAsync(d_ws, 0, zeroBytes, stream);
  k_count<<<(RE + 255) / 256, 256, 0, stream>>>(deg, en, RE);
  k_count<<<(R5 + 255) / 256, 256, 0, stream>>>(d5, cn5, R5);
  k_count<<<(R6 + 255) / 256, 256, 0, stream>>>(d6, cn6, R6);
  k_scales<<<(N + 255) / 256, 256, 0, stream>>>(deg, d5, d6, deg2, dd, N);
  wtr(nm_w1, WtNm1, 896, 256);  wtr(em_w1, WtEm1, 896, 256);
  wtr(ce_w1, WtCe1, 1408, 256); wtr(cm_w1, WtCm1, 640, 256);
  wtr(nm_w2, WtNm2, 256, 128);  wtr(em_w2, WtEm2, 256, 128);
  wtr(ce_w2, WtCe2, 256, 128);  wtr(cm_w2, WtCm2, 256, 128);
  wtr(fm_w,  WtFm,  256, 128);

  // ---- phase 1: edge-node tables ----
  gsum(s2, 128, edge_rep, 128, nullptr, nullptr, 2, E);
  gsum(sN, 128, node_rep, 128, nullptr, en, 2, E);
  scat(Ae, edge_rep, en, RE, 128, 1);
  scat(Be, s2, en, RE, 128, 2);
  scat(Bn, sN, en, RE, 128, 2);
  gsum(s3, 256, Ae, 128, nullptr, en, 2, E);
  gsum(s3 + 128, 256, Be, 128, nullptr, en, 2, E);
  scat(pb2, s3, en, RE, 256, 2);

  // ---- phase 2: cycle tables ----
  gsum(s5, 256, Ae, 128, nullptr, cn5, 5, C5);
  gsum(s5 + 128, 256, Be, 128, nullptr, cn5, 5, C5);
  gsum(s6, 256, Ae, 128, nullptr, cn6, 6, C6);
  gsum(s6 + 128, 256, Be, 128, nullptr, cn6, 6, C6);
  scat(pb5, s5, cn5, R5, 256, 5);
  scat(pb6, s6, cn6, R6, 256, 6);
  scat(Ac, cycle_rep, cn5, R5, 128, 1);
  scat(Ac, cycle_rep + (size_t)R5 * 128, cn6, R6, 128, 1);

  // ---- ce stage ----
  gsum(scb + 0,   640, Ae, 128, d5, cn5, 5, C5);
  gsum(scb + 128, 640, Be, 128, d5, cn5, 5, C5);
  gsum(scb + 256, 640, pb5, 256, nullptr, cn5, 5, C5);
  gsum(scb + 384, 640, pb5 + 128, 256, nullptr, cn5, 5, C5);
  gsum(scb + 512, 640, cycle_rep, 128, nullptr, nullptr, 5, C5);
  float* sc6 = scb + (size_t)C5 * 640;
  gsum(sc6 + 0,   640, Ae, 128, d6, cn6, 6, C6);
  gsum(sc6 + 128, 640, Be, 128, d6, cn6, 6, C6);
  gsum(sc6 + 256, 640, pb6, 256, nullptr, cn6, 6, C6);
  gsum(sc6 + 384, 640, pb6 + 128, 256, nullptr, cn6, 6, C6);
  gsum(sc6 + 512, 640, cycle_rep + (size_t)R5 * 128, 128, nullptr, nullptr, 6, C6);
  gemm({{scb, nullptr, nullptr, 640, 768, 0}, {scb + 128, nullptr, nullptr, 640, 896, 0},
        {scb + 256, nullptr, nullptr, 640, 1024, 0}, {scb + 384, nullptr, nullptr, 640, 1152, 0},
        {scb + 512, nullptr, nullptr, 640, 1280, 0}},
       WtCe1, 1408, 256, Ysc, CC, false, nullptr, nullptr);
  gemm({{Ae, nullptr, dd, 128, 128, 0}, {Be, nullptr, dd, 128, 256, 0},
        {pb5, nullptr, d5, 256, 384, 0}, {pb5 + 128, nullptr, d5, 256, 512, 0},
        {pb6, nullptr, d6, 256, 384, 0}, {pb6 + 128, nullptr, d6, 256, 512, 0},
        {Ac, nullptr, nullptr, 128, 640, 0}},
       WtCe1, 1408, 256, Z, N, false, nullptr, nullptr);
  scat(Z, Ysc, cn5, R5, 256, 5);
  scat(Z, Ysc + (size_t)C5 * 256, cn6, R6, 256, 6);
  gemm({{edge_rep, nullptr, nullptr, 128, 0, 0}}, WtCe1, 1408, 256, Yb, RE, true, Z, en);
  bn(Yb, Yb, ce_g1, ce_b1, RE, 256, 1, 1);
  gemm({{Yb, nullptr, nullptr, 256, 0, 1}, {Yb + 256, nullptr, nullptr, 256, 128, 1}},
       WtCe2, 256, 128, O2, RE, true, nullptr, nullptr);
  bn(O2, O2, ce_g2, ce_b2, RE, 128, 1, 1);

  // ---- em stage ----
  gemm({{Ae, nullptr, deg, 128, 128, 0}, {Be, nullptr, deg, 128, 256, 0},
        {pb2, nullptr, nullptr, 256, 384, 0}, {pb2 + 128, nullptr, nullptr, 256, 512, 0},
        {node_rep, nullptr, deg, 128, 640, 0}, {Bn, nullptr, nullptr, 128, 768, 0}},
       WtEm1, 896, 256, Z, N, false, nullptr, nullptr);
  gemm({{edge_rep, nullptr, nullptr, 128, 0, 0}}, WtEm1, 896, 256, Yb, RE, true, Z, en);
  bn(Yb, Yb, em_g1, em_b1, RE, 256, 1, 1);
  gemm({{Yb, nullptr, nullptr, 256, 0, 1}, {Yb + 256, nullptr, nullptr, 256, 128, 1}},
       WtEm2, 256, 128, outE, RE, false, nullptr, nullptr);   // out1 -> outD edge region (scratch)
  bn(outE, outE, em_g2, em_b2, RE, 128, 0, 0);

  // ---- nm stage ----
  gemm({{node_rep, nullptr, nullptr, 128, 0, 0}, {Ae, nullptr, deg2, 128, 128, 0},
        {Be, nullptr, deg2, 128, 256, 0}, {pb2, nullptr, deg, 256, 384, 0},
        {pb2 + 128, nullptr, deg, 256, 512, 0}, {node_rep, nullptr, deg2, 128, 640, 0},
        {Bn, nullptr, deg, 128, 768, 0}},
       WtNm1, 896, 256, Yb, N, true, nullptr, nullptr);
  bn(Yb, Yb, nm_g1, nm_b1, N, 256, 1, 1);
  gemm({{Yb, nullptr, nullptr, 256, 0, 1}, {Yb + 256, nullptr, nullptr, 256, 128, 1}},
       WtNm2, 256, 128, outN, N, false, nullptr, nullptr);
  bn(outN, outN, nm_g2, nm_b2, N, 128, 0, 0);

  // ---- cm stage ----
  gemm({{Ae, nullptr, d5, 128, 0, 0}, {Be, nullptr, d5, 128, 128, 0},
        {pb5, nullptr, nullptr, 256, 256, 0}, {pb5 + 128, nullptr, nullptr, 256, 384, 0}},
       WtCm1, 640, 256, Z, N, false, nullptr, nullptr);
  gemm({{cycle_rep, nullptr, nullptr, 128, 512, 0}}, WtCm1, 640, 256, Yb, R5, true, Z, cn5);
  gemm({{Ae, nullptr, d6, 128, 0, 0}, {Be, nullptr, d6, 128, 128, 0},
        {pb6, nullptr, nullptr, 256, 256, 0}, {pb6 + 128, nullptr, nullptr, 256, 384, 0}},
       WtCm1, 640, 256, Z, N, false, nullptr, nullptr);
  gemm({{cycle_rep + (size_t)R5 * 128, nullptr, nullptr, 128, 512, 0}}, WtCm1, 640, 256,
       Yb + (size_t)R5 * 256 * 2, R6, true, Z, cn6);
  bn(Yb, Yb, cm_g1, cm_b1, NC, 256, 1, 1);
  gemm({{Yb, nullptr, nullptr, 256, 0, 1}, {Yb + 256, nullptr, nullptr, 256, 128, 1}},
       WtCm2, 256, 128, outC, NC, false, nullptr, nullptr);
  bn(outC, outC, cm_g2, cm_b2, NC, 128, 0, 0);

  // ---- fm stage ----
  gemm({{outE, nullptr, nullptr, 128, 0, 0}, {O2, nullptr, nullptr, 128, 128, 1}},
       WtFm, 256, 128, Yb, RE, true, nullptr, nullptr);
  bn(Yb, outE, fm_g, fm_b, RE, 128, 1, 0);
}